// Round 22
// baseline (303.561 us; speedup 1.0000x reference)
//
#include <hip/hip_runtime.h>
#include <math.h>

#define TOK 4096
#define D 1024
#define DFF 4096
#define NE 8
#define CAP 4096
#define YSLOTS 9216
#define GTOK 16

typedef _Float16 half4v __attribute__((ext_vector_type(4)));
typedef _Float16 half8v __attribute__((ext_vector_type(8)));
typedef float f32x4 __attribute__((ext_vector_type(4)));
typedef float f32x16 __attribute__((ext_vector_type(16)));

#define GLOAD16(gp, lp) __builtin_amdgcn_global_load_lds( \
    (const __attribute__((address_space(1))) void*)(gp),  \
    (__attribute__((address_space(3))) void*)(lp), 16, 0, 0)

__device__ __forceinline__ float fast_gelu(float v) {
    float u = 0.7978845608f * (v + 0.044715f * v * v * v);
    float au = fabsf(u);
    float t = __expf(-2.f * au);
    float th = (1.f - t) / (1.f + t);
    th = u < 0.f ? -th : th;
    return 0.5f * v * (1.f + th);
}

// padded (128) prefix offsets computed in-registers from counts
__device__ __forceinline__ void mk_offs(const int* __restrict__ counts, int* offE) {
    offE[0] = 0;
#pragma unroll
    for (int k = 0; k < NE; ++k) offE[k + 1] = offE[k] + ((counts[k] + 127) & ~127);
}

// transpose+convert one 128r x 64c tile: fp32 S[R][C] -> fp16 T[C][R]
__device__ __forceinline__ void tr_tile(const float* __restrict__ S,
                                        _Float16* __restrict__ T,
                                        int R, int C, int r0, int c0,
                                        char* smem, int tid) {
    float (*tile_t)[129] = (float(*)[129])smem;
    int cl = tid & 63;
    int rl = (tid >> 6) * 32;
#pragma unroll
    for (int k = 0; k < 32; ++k) {
        int r = rl + k;
        tile_t[cl][r] = S[(size_t)(r0 + r) * C + c0 + cl];
    }
    __syncthreads();
    int j = tid & 7;
#pragma unroll
    for (int p = 0; p < 2; ++p) {
        int c = p * 32 + (tid >> 3);
#pragma unroll
        for (int i = 0; i < 2; ++i) {
            int rb = i * 64 + j * 8;
            half8v h;
#pragma unroll
            for (int jj = 0; jj < 8; ++jj) h[jj] = (_Float16)tile_t[c][rb + jj];
            *(half8v*)(T + (size_t)(c0 + c) * R + r0 + rb) = h;
        }
    }
}

// ---------------- ws layout (bytes) ----------------
// 0       counts[8]; 256 tk_e; 33024 tk_w; 65792 tk_pos; 98560 tok_list
// 1 MiB   xh fp16 [TOK][D]           (8 MiB)
// 10 MiB  W1t fp16 [E][DFF][D]       (64 MiB)  <- Yh fp16 [2][YSLOTS][D] overlays after ffn1
// 74 MiB  W2t fp16 [E][D][DFF]       (64 MiB)
// 138 MiB H fp16 [YSLOTS][DFF]       (75.5 MB)

// Fused A: blocks [0,256) gate + x cvt; blocks [256,256+4096) transpose W1.
__global__ void k_gate_trw1(const float* __restrict__ x, const float* __restrict__ Wg,
                            const float* __restrict__ bg, int* __restrict__ counts,
                            int* __restrict__ tk_e, float* __restrict__ tk_w,
                            int* __restrict__ tk_pos, int* __restrict__ tok_list,
                            _Float16* __restrict__ xh,
                            const float* __restrict__ W1, _Float16* __restrict__ W1t) {
    __shared__ __align__(16) char smem[33024];
    int bid = blockIdx.x;
    int tid = threadIdx.x;
    if (bid >= 256) {
        int t = bid - 256;
        int e = t >> 9, xx = t & 511;
        tr_tile(W1 + (size_t)e * D * DFF, W1t + (size_t)e * DFF * D,
                D, DFF, (xx >> 6) * 128, (xx & 63) * 64, smem, tid);
        return;
    }
    int* s_e = (int*)smem;
    int* s_rank = (int*)(smem + 128);
    int* s_base = (int*)(smem + 256);
    int wid = tid >> 6, lane = tid & 63;
    int tbase = bid * GTOK;

    for (int i = 0; i < 4; ++i) {
        int tl = wid * 4 + i;
        int t = tbase + tl;
        const float* xr = x + (size_t)t * D;
        float a[NE];
#pragma unroll
        for (int e = 0; e < NE; ++e) a[e] = 0.f;
        for (int d = lane; d < D; d += 64) {
            float xv = xr[d];
            const float4 w0 = *(const float4*)(Wg + d * NE);
            const float4 w1 = *(const float4*)(Wg + d * NE + 4);
            a[0] += xv * w0.x; a[1] += xv * w0.y; a[2] += xv * w0.z; a[3] += xv * w0.w;
            a[4] += xv * w1.x; a[5] += xv * w1.y; a[6] += xv * w1.z; a[7] += xv * w1.w;
        }
#pragma unroll
        for (int j = 0; j < 2; ++j) {
            int ch = j * 64 + lane;
            float4 va = *(const float4*)(xr + ch * 8);
            float4 vb = *(const float4*)(xr + ch * 8 + 4);
            half8v h;
            h[0] = (_Float16)va.x; h[1] = (_Float16)va.y; h[2] = (_Float16)va.z; h[3] = (_Float16)va.w;
            h[4] = (_Float16)vb.x; h[5] = (_Float16)vb.y; h[6] = (_Float16)vb.z; h[7] = (_Float16)vb.w;
            *(half8v*)(xh + (size_t)t * D + ch * 8) = h;
        }
#pragma unroll
        for (int m = 1; m < 64; m <<= 1) {
#pragma unroll
            for (int e = 0; e < NE; ++e) a[e] += __shfl_xor(a[e], m, 64);
        }
        if (lane == 0) {
#pragma unroll
            for (int e = 0; e < NE; ++e) a[e] += bg[e];
            int i0 = 0;
#pragma unroll
            for (int e = 1; e < NE; ++e) if (a[e] > a[i0]) i0 = e;
            int i1 = (i0 == 0) ? 1 : 0;
#pragma unroll
            for (int e = 0; e < NE; ++e) if (e != i0 && a[e] > a[i1]) i1 = e;
            float ee = expf(a[i1] - a[i0]);
            float w0 = 1.f / (1.f + ee);
            float w1 = ee / (1.f + ee);
            tk_e[t * 2] = i0; tk_e[t * 2 + 1] = i1;
            tk_w[t * 2] = w0; tk_w[t * 2 + 1] = w1;
            s_e[tl * 2] = i0; s_e[tl * 2 + 1] = i1;
        }
    }
    __syncthreads();
    if (tid < 2 * GTOK) {
        int ei = s_e[tid];
        int r = 0;
#pragma unroll
        for (int j = 0; j < 2 * GTOK; ++j) r += (j < tid && s_e[j] == ei) ? 1 : 0;
        s_rank[tid] = r;
    } else if (tid >= 64 && tid < 64 + NE) {
        int e = tid - 64;
        int cnt = 0;
#pragma unroll
        for (int j = 0; j < 2 * GTOK; ++j) cnt += (s_e[j] == e) ? 1 : 0;
        s_base[e] = cnt ? atomicAdd(&counts[e], cnt) : 0;
    }
    __syncthreads();
    if (tid < 2 * GTOK) {
        int ei = s_e[tid];
        int t = tbase + (tid >> 1);
        int pos = s_base[ei] + s_rank[tid];
        tok_list[ei * CAP + pos] = t;
        tk_pos[t * 2 + (tid & 1)] = pos;
    }
}

// Fused B (interleaved): 6400 = 256 x 25; r<9 -> GEMM1 (32x32x16 MFMA), r>=9 -> trW2.
__global__ __launch_bounds__(256, 4)
void k_ffn1_trw2(const _Float16* __restrict__ xh, const _Float16* __restrict__ W1t,
                 const float* __restrict__ b1, const int* __restrict__ counts,
                 const int* __restrict__ tok_list, _Float16* __restrict__ H,
                 const float* __restrict__ W2, _Float16* __restrict__ W2t) {
    __shared__ __align__(16) char smem[34816];
    int bid = blockIdx.x;
    int tid = threadIdx.x;
    int q = bid / 25, r = bid % 25;
    if (r >= 9) {
        int t = q * 16 + (r - 9);
        int e = t >> 9, xx = t & 511;
        tr_tile(W2 + (size_t)e * DFF * D, W2t + (size_t)e * D * DFF,
                DFF, D, (xx >> 4) * 128, (xx & 15) * 64, smem, tid);
        return;
    }
    int gid = q * 9 + r;
    int offE[NE + 1];
    mk_offs(counts, offE);
    int T = gid >> 5;
    if (T * 128 >= offE[NE]) return;
    int e = 0;
#pragma unroll
    for (int k = 1; k < NE; ++k) if (offE[k] <= T * 128) e = k;
    int row0 = T * 128 - offE[e];
    int n_e = counts[e];
    int bx = gid & 31;

    _Float16* As = (_Float16*)smem;                    // 16 KB
    _Float16* Bs = (_Float16*)(smem + 16384);          // 16 KB
    int* s_tok = (int*)(smem + 32768);                 // 512 B

    int lane = tid & 63, wid = tid >> 6;
    if (tid < 128) {
        int m = row0 + tid;
        s_tok[tid] = tok_list[e * CAP + (m < n_e ? m : n_e - 1)];
    }
    __syncthreads();

    int srow = lane >> 3, u = lane & 7;
    int wm = (wid >> 1) * 64, wn = (wid & 1) * 64;
    int r31 = lane & 31, l5 = lane >> 5;
    int v8 = u ^ srow;
    int rbase = wid * 32 + srow;

    const _Float16* Abase = W1t + (size_t)e * DFF * D + (size_t)(bx * 128) * D + v8 * 8;
    const _Float16* bsrc[4];
#pragma unroll
    for (int i = 0; i < 4; ++i)
        bsrc[i] = xh + (size_t)s_tok[rbase + i * 8] * D + v8 * 8;

    f32x16 acc[2][2];
#pragma unroll
    for (int i = 0; i < 2; ++i)
#pragma unroll
        for (int j = 0; j < 2; ++j) acc[i][j] = (f32x16)0.f;

    for (int kt = 0; kt < D; kt += 64) {
#pragma unroll
        for (int i = 0; i < 4; ++i)
            GLOAD16(Abase + (size_t)(rbase + i * 8) * D + kt, As + (wid * 4 + i) * 512);
#pragma unroll
        for (int i = 0; i < 4; ++i)
            GLOAD16(bsrc[i] + kt, Bs + (wid * 4 + i) * 512);
        __syncthreads();
#pragma unroll
        for (int ks = 0; ks < 4; ++ks) {
            int uu = ((ks * 2 + l5) ^ (r31 & 7)) * 8;
            half8v aF0 = *(const half8v*)(As + (wm + r31) * 64 + uu);
            half8v aF1 = *(const half8v*)(As + (wm + 32 + r31) * 64 + uu);
            half8v bF0 = *(const half8v*)(Bs + (wn + r31) * 64 + uu);
            half8v bF1 = *(const half8v*)(Bs + (wn + 32 + r31) * 64 + uu);
            acc[0][0] = __builtin_amdgcn_mfma_f32_32x32x16_f16(aF0, bF0, acc[0][0], 0, 0, 0);
            acc[0][1] = __builtin_amdgcn_mfma_f32_32x32x16_f16(aF0, bF1, acc[0][1], 0, 0, 0);
            acc[1][0] = __builtin_amdgcn_mfma_f32_32x32x16_f16(aF1, bF0, acc[1][0], 0, 0, 0);
            acc[1][1] = __builtin_amdgcn_mfma_f32_32x32x16_f16(aF1, bF1, acc[1][1], 0, 0, 0);
        }
        __syncthreads();
    }

    // epilogue: bias + fast gelu; C/D: col=lane&31 (slot), row=(reg&3)+8*(reg>>2)+4*l5 (feat)
    _Float16* Tile = (_Float16*)smem;  // [128 slots][136]
#pragma unroll
    for (int fm2 = 0; fm2 < 2; ++fm2) {
#pragma unroll
        for (int qq = 0; qq < 4; ++qq) {
            int featl = wm + fm2 * 32 + qq * 8 + l5 * 4;
            float4 bv = *(const float4*)(b1 + e * DFF + bx * 128 + featl);
            float bb[4] = {bv.x, bv.y, bv.z, bv.w};
#pragma unroll
            for (int fn2 = 0; fn2 < 2; ++fn2) {
                int sl = wn + fn2 * 32 + r31;
                half4v hv;
#pragma unroll
                for (int j = 0; j < 4; ++j) {
                    float vv2 = acc[fm2][fn2][qq * 4 + j] + bb[j];
                    hv[j] = (_Float16)fast_gelu(vv2);
                }
                *(half4v*)(&Tile[sl * 136 + featl]) = hv;
            }
        }
    }
    __syncthreads();
#pragma unroll
    for (int p = 0; p < 8; ++p) {
        int r2 = p * 16 + (tid >> 4);
        int c8 = (tid & 15) * 8;
        if (row0 + r2 < n_e)
            *(half8v*)(H + (size_t)(T * 128 + r2) * DFF + bx * 128 + c8) =
                *(const half8v*)(&Tile[r2 * 136 + c8]);
    }
}

// GEMM2 (split-K=2, 32x32x16 MFMA): Y[kh][slot][D] partials; 1-D XCD-aware grid
__global__ __launch_bounds__(256, 4)
void k_ffn2(const _Float16* __restrict__ H, const _Float16* __restrict__ W2t,
            const int* __restrict__ counts, _Float16* __restrict__ Yh) {
    int wg = blockIdx.x;
    int xcd = wg & 7, j = wg >> 3;        // j in [0,144)
    int bx = j & 7;
    int tl = (j >> 3) % 9;
    int kh = j / 72;
    int T = xcd * 9 + tl;
    int offE[NE + 1];
    mk_offs(counts, offE);
    if (T * 128 >= offE[NE]) return;
    int e = 0;
#pragma unroll
    for (int k = 1; k < NE; ++k) if (offE[k] <= T * 128) e = k;
    int row0 = T * 128 - offE[e];
    int n_e = counts[e];

    __shared__ __align__(16) char smem[34816];
    _Float16* As = (_Float16*)smem;
    _Float16* Bs = (_Float16*)(smem + 16384);

    int tid = threadIdx.x, lane = tid & 63, wid = tid >> 6;
    int srow = lane >> 3, u = lane & 7;
    int wm = (wid >> 1) * 64, wn = (wid & 1) * 64;
    int r31 = lane & 31, l5 = lane >> 5;
    int v8 = u ^ srow;
    int rbase = wid * 32 + srow;

    const _Float16* Abase = W2t + (size_t)e * D * DFF + (size_t)(bx * 128) * DFF + v8 * 8;
    const _Float16* Bbase = H + (size_t)(T * 128) * DFF + v8 * 8;

    f32x16 acc[2][2];
#pragma unroll
    for (int i = 0; i < 2; ++i)
#pragma unroll
        for (int j2 = 0; j2 < 2; ++j2) acc[i][j2] = (f32x16)0.f;

    int kt0 = kh * 2048, kt1 = kt0 + 2048;
    for (int kt = kt0; kt < kt1; kt += 64) {
#pragma unroll
        for (int i = 0; i < 4; ++i)
            GLOAD16(Abase + (size_t)(rbase + i * 8) * DFF + kt, As + (wid * 4 + i) * 512);
#pragma unroll
        for (int i = 0; i < 4; ++i)
            GLOAD16(Bbase + (size_t)(rbase + i * 8) * DFF + kt, Bs + (wid * 4 + i) * 512);
        __syncthreads();
#pragma unroll
        for (int ks = 0; ks < 4; ++ks) {
            int uu = ((ks * 2 + l5) ^ (r31 & 7)) * 8;
            half8v aF0 = *(const half8v*)(As + (wm + r31) * 64 + uu);
            half8v aF1 = *(const half8v*)(As + (wm + 32 + r31) * 64 + uu);
            half8v bF0 = *(const half8v*)(Bs + (wn + r31) * 64 + uu);
            half8v bF1 = *(const half8v*)(Bs + (wn + 32 + r31) * 64 + uu);
            acc[0][0] = __builtin_amdgcn_mfma_f32_32x32x16_f16(aF0, bF0, acc[0][0], 0, 0, 0);
            acc[0][1] = __builtin_amdgcn_mfma_f32_32x32x16_f16(aF0, bF1, acc[0][1], 0, 0, 0);
            acc[1][0] = __builtin_amdgcn_mfma_f32_32x32x16_f16(aF1, bF0, acc[1][0], 0, 0, 0);
            acc[1][1] = __builtin_amdgcn_mfma_f32_32x32x16_f16(aF1, bF1, acc[1][1], 0, 0, 0);
        }
        __syncthreads();
    }

    _Float16* Tile = (_Float16*)smem;  // [128 slots][136]
#pragma unroll
    for (int fm2 = 0; fm2 < 2; ++fm2) {
#pragma unroll
        for (int qq = 0; qq < 4; ++qq) {
            int dl = wm + fm2 * 32 + qq * 8 + l5 * 4;
#pragma unroll
            for (int fn2 = 0; fn2 < 2; ++fn2) {
                int sl = wn + fn2 * 32 + r31;
                half4v hv;
#pragma unroll
                for (int j2 = 0; j2 < 4; ++j2) hv[j2] = (_Float16)acc[fm2][fn2][qq * 4 + j2];
                *(half4v*)(&Tile[sl * 136 + dl]) = hv;
            }
        }
    }
    __syncthreads();
#pragma unroll
    for (int p = 0; p < 8; ++p) {
        int r = p * 16 + (tid >> 4);
        int c8 = (tid & 15) * 8;
        if (row0 + r < n_e)
            *(half8v*)(Yh + ((size_t)kh * YSLOTS + T * 128 + r) * D + bx * 128 + c8) =
                *(const half8v*)(&Tile[r * 136 + c8]);
    }
}

__global__ void k_comb(const int* __restrict__ tk_e, const float* __restrict__ tk_w,
                       const int* __restrict__ tk_pos, const int* __restrict__ counts,
                       const _Float16* __restrict__ Yh, const float* __restrict__ b2,
                       float* __restrict__ out) {
    int idx = blockIdx.x * 256 + threadIdx.x;
    int t = idx >> 8;
    int d = (idx & 255) * 4;
    int offE[NE + 1];
    mk_offs(counts, offE);
    int e0 = tk_e[2 * t], e1 = tk_e[2 * t + 1];
    float w0 = tk_w[2 * t], w1 = tk_w[2 * t + 1];
    size_t s0 = offE[e0] + tk_pos[2 * t];
    size_t s1 = offE[e1] + tk_pos[2 * t + 1];
    half4v y00 = *(const half4v*)(Yh + s0 * D + d);
    half4v y01 = *(const half4v*)(Yh + ((size_t)YSLOTS + s0) * D + d);
    half4v y10 = *(const half4v*)(Yh + s1 * D + d);
    half4v y11 = *(const half4v*)(Yh + ((size_t)YSLOTS + s1) * D + d);
    float4 b20 = *(const float4*)(b2 + e0 * D + d);
    float4 b21 = *(const float4*)(b2 + e1 * D + d);
    float4 r;
    r.x = w0 * ((float)y00[0] + (float)y01[0] + b20.x) + w1 * ((float)y10[0] + (float)y11[0] + b21.x);
    r.y = w0 * ((float)y00[1] + (float)y01[1] + b20.y) + w1 * ((float)y10[1] + (float)y11[1] + b21.y);
    r.z = w0 * ((float)y00[2] + (float)y01[2] + b20.z) + w1 * ((float)y10[2] + (float)y11[2] + b21.z);
    r.w = w0 * ((float)y00[3] + (float)y01[3] + b20.w) + w1 * ((float)y10[3] + (float)y11[3] + b21.w);
    *(float4*)(out + (size_t)t * D + d) = r;
}

extern "C" void kernel_launch(void* const* d_in, const int* in_sizes, int n_in,
                              void* d_out, int out_size, void* d_ws, size_t ws_size,
                              hipStream_t stream) {
    const float* x  = (const float*)d_in[0];
    const float* W1 = (const float*)d_in[1];
    const float* b1 = (const float*)d_in[2];
    const float* W2 = (const float*)d_in[3];
    const float* b2 = (const float*)d_in[4];
    const float* Wg = (const float*)d_in[5];
    const float* bg = (const float*)d_in[6];
    float* out = (float*)d_out;

    char* ws = (char*)d_ws;
    int*   counts   = (int*)(ws);
    int*   tk_e     = (int*)(ws + 256);
    float* tk_w     = (float*)(ws + 33024);
    int*   tk_pos   = (int*)(ws + 65792);
    int*   tok_list = (int*)(ws + 98560);
    _Float16* xh    = (_Float16*)(ws + (1ull << 20));
    _Float16* W1t   = (_Float16*)(ws + (10ull << 20));
    _Float16* Yh    = (_Float16*)(ws + (10ull << 20));   // overlays W1t after ffn1
    _Float16* W2t   = (_Float16*)(ws + (74ull << 20));
    _Float16* H     = (_Float16*)(ws + (138ull << 20));

    hipMemsetAsync(counts, 0, 64, stream);
    k_gate_trw1<<<256 + 4096, 256, 0, stream>>>(x, Wg, bg, counts, tk_e, tk_w, tk_pos,
                                                tok_list, xh, W1, W1t);
    k_ffn1_trw2<<<2304 + 4096, 256, 0, stream>>>(xh, W1t, b1, counts, tok_list,
                                                 H, W2, W2t);
    k_ffn2<<<8 * 144, 256, 0, stream>>>(H, W2t, counts, Yh);
    k_comb<<<(TOK * D / 4) / 256, 256, 0, stream>>>(tk_e, tk_w, tk_pos, counts, Yh, b2, out);
}

// Round 23
// 293.784 us; speedup vs baseline: 1.0333x; 1.0333x over previous
//
#include <hip/hip_runtime.h>
#include <math.h>

#define TOK 4096
#define D 1024
#define DFF 4096
#define NE 8
#define CAP 4096
#define YSLOTS 9216
#define GTOK 16

typedef _Float16 half4v __attribute__((ext_vector_type(4)));
typedef _Float16 half8v __attribute__((ext_vector_type(8)));
typedef float f32x4 __attribute__((ext_vector_type(4)));

#define GLOAD16(gp, lp) __builtin_amdgcn_global_load_lds( \
    (const __attribute__((address_space(1))) void*)(gp),  \
    (__attribute__((address_space(3))) void*)(lp), 16, 0, 0)

__device__ __forceinline__ float fast_gelu(float v) {
    float u = 0.7978845608f * (v + 0.044715f * v * v * v);
    float au = fabsf(u);
    float t = __expf(-2.f * au);
    float th = (1.f - t) / (1.f + t);
    th = u < 0.f ? -th : th;
    return 0.5f * v * (1.f + th);
}

// padded (128) prefix offsets computed in-registers from counts
__device__ __forceinline__ void mk_offs(const int* __restrict__ counts, int* offE) {
    offE[0] = 0;
#pragma unroll
    for (int k = 0; k < NE; ++k) offE[k + 1] = offE[k] + ((counts[k] + 127) & ~127);
}

// transpose+convert one 128r x 64c tile: fp32 S[R][C] -> fp16 T[C][R]
__device__ __forceinline__ void tr_tile(const float* __restrict__ S,
                                        _Float16* __restrict__ T,
                                        int R, int C, int r0, int c0,
                                        char* smem, int tid) {
    float (*tile_t)[129] = (float(*)[129])smem;
    int cl = tid & 63;
    int rl = (tid >> 6) * 32;
#pragma unroll
    for (int k = 0; k < 32; ++k) {
        int r = rl + k;
        tile_t[cl][r] = S[(size_t)(r0 + r) * C + c0 + cl];
    }
    __syncthreads();
    int j = tid & 7;
#pragma unroll
    for (int p = 0; p < 2; ++p) {
        int c = p * 32 + (tid >> 3);
#pragma unroll
        for (int i = 0; i < 2; ++i) {
            int rb = i * 64 + j * 8;
            half8v h;
#pragma unroll
            for (int jj = 0; jj < 8; ++jj) h[jj] = (_Float16)tile_t[c][rb + jj];
            *(half8v*)(T + (size_t)(c0 + c) * R + r0 + rb) = h;
        }
    }
}

// ---------------- ws layout (bytes) ----------------
// 0       counts[8]; 256 tk_e; 33024 tk_w; 65792 tk_pos; 98560 tok_list
// 1 MiB   xh fp16 [TOK][D]           (8 MiB)
// 10 MiB  W1t fp16 [E][DFF][D]       (64 MiB)  <- Yh fp16 [2][YSLOTS][D] overlays after ffn1
// 74 MiB  W2t fp16 [E][D][DFF]       (64 MiB)
// 138 MiB H fp16 [YSLOTS][DFF]       (75.5 MB)

// Fused A: blocks [0,256) gate + x cvt; blocks [256,256+4096) transpose W1.
__global__ void k_gate_trw1(const float* __restrict__ x, const float* __restrict__ Wg,
                            const float* __restrict__ bg, int* __restrict__ counts,
                            int* __restrict__ tk_e, float* __restrict__ tk_w,
                            int* __restrict__ tk_pos, int* __restrict__ tok_list,
                            _Float16* __restrict__ xh,
                            const float* __restrict__ W1, _Float16* __restrict__ W1t) {
    __shared__ __align__(16) char smem[33024];
    int bid = blockIdx.x;
    int tid = threadIdx.x;
    if (bid >= 256) {
        int t = bid - 256;
        int e = t >> 9, xx = t & 511;
        tr_tile(W1 + (size_t)e * D * DFF, W1t + (size_t)e * DFF * D,
                D, DFF, (xx >> 6) * 128, (xx & 63) * 64, smem, tid);
        return;
    }
    int* s_e = (int*)smem;
    int* s_rank = (int*)(smem + 128);
    int* s_base = (int*)(smem + 256);
    int wid = tid >> 6, lane = tid & 63;
    int tbase = bid * GTOK;

    for (int i = 0; i < 4; ++i) {
        int tl = wid * 4 + i;
        int t = tbase + tl;
        const float* xr = x + (size_t)t * D;
        float a[NE];
#pragma unroll
        for (int e = 0; e < NE; ++e) a[e] = 0.f;
        for (int d = lane; d < D; d += 64) {
            float xv = xr[d];
            const float4 w0 = *(const float4*)(Wg + d * NE);
            const float4 w1 = *(const float4*)(Wg + d * NE + 4);
            a[0] += xv * w0.x; a[1] += xv * w0.y; a[2] += xv * w0.z; a[3] += xv * w0.w;
            a[4] += xv * w1.x; a[5] += xv * w1.y; a[6] += xv * w1.z; a[7] += xv * w1.w;
        }
#pragma unroll
        for (int j = 0; j < 2; ++j) {
            int ch = j * 64 + lane;
            float4 va = *(const float4*)(xr + ch * 8);
            float4 vb = *(const float4*)(xr + ch * 8 + 4);
            half8v h;
            h[0] = (_Float16)va.x; h[1] = (_Float16)va.y; h[2] = (_Float16)va.z; h[3] = (_Float16)va.w;
            h[4] = (_Float16)vb.x; h[5] = (_Float16)vb.y; h[6] = (_Float16)vb.z; h[7] = (_Float16)vb.w;
            *(half8v*)(xh + (size_t)t * D + ch * 8) = h;
        }
#pragma unroll
        for (int m = 1; m < 64; m <<= 1) {
#pragma unroll
            for (int e = 0; e < NE; ++e) a[e] += __shfl_xor(a[e], m, 64);
        }
        if (lane == 0) {
#pragma unroll
            for (int e = 0; e < NE; ++e) a[e] += bg[e];
            int i0 = 0;
#pragma unroll
            for (int e = 1; e < NE; ++e) if (a[e] > a[i0]) i0 = e;
            int i1 = (i0 == 0) ? 1 : 0;
#pragma unroll
            for (int e = 0; e < NE; ++e) if (e != i0 && a[e] > a[i1]) i1 = e;
            float ee = expf(a[i1] - a[i0]);
            float w0 = 1.f / (1.f + ee);
            float w1 = ee / (1.f + ee);
            tk_e[t * 2] = i0; tk_e[t * 2 + 1] = i1;
            tk_w[t * 2] = w0; tk_w[t * 2 + 1] = w1;
            s_e[tl * 2] = i0; s_e[tl * 2 + 1] = i1;
        }
    }
    __syncthreads();
    if (tid < 2 * GTOK) {
        int ei = s_e[tid];
        int r = 0;
#pragma unroll
        for (int j = 0; j < 2 * GTOK; ++j) r += (j < tid && s_e[j] == ei) ? 1 : 0;
        s_rank[tid] = r;
    } else if (tid >= 64 && tid < 64 + NE) {
        int e = tid - 64;
        int cnt = 0;
#pragma unroll
        for (int j = 0; j < 2 * GTOK; ++j) cnt += (s_e[j] == e) ? 1 : 0;
        s_base[e] = cnt ? atomicAdd(&counts[e], cnt) : 0;
    }
    __syncthreads();
    if (tid < 2 * GTOK) {
        int ei = s_e[tid];
        int t = tbase + (tid >> 1);
        int pos = s_base[ei] + s_rank[tid];
        tok_list[ei * CAP + pos] = t;
        tk_pos[t * 2 + (tid & 1)] = pos;
    }
}

// Fused B (interleaved): 6400 = 256 groups x 25; r<9 -> GEMM1 block q*9+r (2304),
// r>=9 -> W2-transpose tile q*16+(r-9) (4096). Keeps compute/BW mix even.
__global__ __launch_bounds__(256, 4)
void k_ffn1_trw2(const _Float16* __restrict__ xh, const _Float16* __restrict__ W1t,
                 const float* __restrict__ b1, const int* __restrict__ counts,
                 const int* __restrict__ tok_list, _Float16* __restrict__ H,
                 const float* __restrict__ W2, _Float16* __restrict__ W2t) {
    __shared__ __align__(16) char smem[34816];
    int bid = blockIdx.x;
    int tid = threadIdx.x;
    int q = bid / 25, r = bid % 25;
    if (r >= 9) {
        int t = q * 16 + (r - 9);
        int e = t >> 9, xx = t & 511;
        tr_tile(W2 + (size_t)e * DFF * D, W2t + (size_t)e * D * DFF,
                DFF, D, (xx >> 4) * 128, (xx & 15) * 64, smem, tid);
        return;
    }
    int gid = q * 9 + r;
    int offE[NE + 1];
    mk_offs(counts, offE);
    int T = gid >> 5;
    if (T * 128 >= offE[NE]) return;
    int e = 0;
#pragma unroll
    for (int k = 1; k < NE; ++k) if (offE[k] <= T * 128) e = k;
    int row0 = T * 128 - offE[e];
    int n_e = counts[e];
    int bx = gid & 31;

    _Float16* As = (_Float16*)smem;                    // 16 KB
    _Float16* Bs = (_Float16*)(smem + 16384);          // 16 KB
    int* s_tok = (int*)(smem + 32768);                 // 512 B

    int lane = tid & 63, wid = tid >> 6;
    if (tid < 128) {
        int m = row0 + tid;
        s_tok[tid] = tok_list[e * CAP + (m < n_e ? m : n_e - 1)];
    }
    __syncthreads();

    int srow = lane >> 3, u = lane & 7;
    int wm = (wid >> 1) * 64, wn = (wid & 1) * 64;
    int cl = lane & 15, g = lane >> 4;
    int v8 = u ^ srow;
    int rbase = wid * 32 + srow;

    const _Float16* Abase = W1t + (size_t)e * DFF * D + (size_t)(bx * 128) * D + v8 * 8;
    const _Float16* bsrc[4];
#pragma unroll
    for (int i = 0; i < 4; ++i)
        bsrc[i] = xh + (size_t)s_tok[rbase + i * 8] * D + v8 * 8;

    f32x4 acc[4][4];
#pragma unroll
    for (int i = 0; i < 4; ++i)
#pragma unroll
        for (int j = 0; j < 4; ++j) acc[i][j] = (f32x4)0.f;

    for (int kt = 0; kt < D; kt += 64) {
#pragma unroll
        for (int i = 0; i < 4; ++i)
            GLOAD16(Abase + (size_t)(rbase + i * 8) * D + kt, As + (wid * 4 + i) * 512);
#pragma unroll
        for (int i = 0; i < 4; ++i)
            GLOAD16(bsrc[i] + kt, Bs + (wid * 4 + i) * 512);
        __syncthreads();
#pragma unroll
        for (int ks = 0; ks < 2; ++ks) {
            half8v aF[4], bF[4];
            int vv = ((ks * 4 + g) ^ (cl & 7)) * 8;
#pragma unroll
            for (int fm = 0; fm < 4; ++fm)
                aF[fm] = *(const half8v*)(As + (wm + fm * 16 + cl) * 64 + vv);
#pragma unroll
            for (int fn = 0; fn < 4; ++fn)
                bF[fn] = *(const half8v*)(Bs + (wn + fn * 16 + cl) * 64 + vv);
#pragma unroll
            for (int fm = 0; fm < 4; ++fm)
#pragma unroll
                for (int fn = 0; fn < 4; ++fn)
                    acc[fm][fn] = __builtin_amdgcn_mfma_f32_16x16x32_f16(aF[fm], bF[fn], acc[fm][fn], 0, 0, 0);
        }
        __syncthreads();
    }

    _Float16* Tile = (_Float16*)smem;  // [128 slots][136]
#pragma unroll
    for (int fm = 0; fm < 4; ++fm) {
        int featl = wm + fm * 16 + g * 4;
        float4 bv = *(const float4*)(b1 + e * DFF + bx * 128 + featl);
        float bb[4] = {bv.x, bv.y, bv.z, bv.w};
#pragma unroll
        for (int fn = 0; fn < 4; ++fn) {
            int sl = wn + fn * 16 + cl;
            half4v hv;
#pragma unroll
            for (int j = 0; j < 4; ++j) {
                float vv2 = acc[fm][fn][j] + bb[j];
                hv[j] = (_Float16)fast_gelu(vv2);
            }
            *(half4v*)(&Tile[sl * 136 + featl]) = hv;
        }
    }
    __syncthreads();
#pragma unroll
    for (int p = 0; p < 8; ++p) {
        int r2 = p * 16 + (tid >> 4);
        int c8 = (tid & 15) * 8;
        if (row0 + r2 < n_e)
            *(half8v*)(H + (size_t)(T * 128 + r2) * DFF + bx * 128 + c8) =
                *(const half8v*)(&Tile[r2 * 136 + c8]);
    }
}

// GEMM2 (split-K=2): Y[kh][slot][D] partials; 1-D XCD-aware grid (1152 blocks)
__global__ __launch_bounds__(256, 4)
void k_ffn2(const _Float16* __restrict__ H, const _Float16* __restrict__ W2t,
            const int* __restrict__ counts, _Float16* __restrict__ Yh) {
    int wg = blockIdx.x;
    int xcd = wg & 7, j = wg >> 3;        // j in [0,144)
    int bx = j & 7;
    int tl = (j >> 3) % 9;
    int kh = j / 72;
    int T = xcd * 9 + tl;
    int offE[NE + 1];
    mk_offs(counts, offE);
    if (T * 128 >= offE[NE]) return;
    int e = 0;
#pragma unroll
    for (int k = 1; k < NE; ++k) if (offE[k] <= T * 128) e = k;
    int row0 = T * 128 - offE[e];
    int n_e = counts[e];

    __shared__ __align__(16) char smem[34816];
    _Float16* As = (_Float16*)smem;
    _Float16* Bs = (_Float16*)(smem + 16384);

    int tid = threadIdx.x, lane = tid & 63, wid = tid >> 6;
    int srow = lane >> 3, u = lane & 7;
    int wm = (wid >> 1) * 64, wn = (wid & 1) * 64;
    int cl = lane & 15, g = lane >> 4;
    int v8 = u ^ srow;
    int rbase = wid * 32 + srow;

    const _Float16* Abase = W2t + (size_t)e * D * DFF + (size_t)(bx * 128) * DFF + v8 * 8;
    const _Float16* Bbase = H + (size_t)(T * 128) * DFF + v8 * 8;

    f32x4 acc[4][4];
#pragma unroll
    for (int i = 0; i < 4; ++i)
#pragma unroll
        for (int j2 = 0; j2 < 4; ++j2) acc[i][j2] = (f32x4)0.f;

    int kt0 = kh * 2048, kt1 = kt0 + 2048;
    for (int kt = kt0; kt < kt1; kt += 64) {
#pragma unroll
        for (int i = 0; i < 4; ++i)
            GLOAD16(Abase + (size_t)(rbase + i * 8) * DFF + kt, As + (wid * 4 + i) * 512);
#pragma unroll
        for (int i = 0; i < 4; ++i)
            GLOAD16(Bbase + (size_t)(rbase + i * 8) * DFF + kt, Bs + (wid * 4 + i) * 512);
        __syncthreads();
#pragma unroll
        for (int ks = 0; ks < 2; ++ks) {
            half8v aF[4], bF[4];
            int vv = ((ks * 4 + g) ^ (cl & 7)) * 8;
#pragma unroll
            for (int fm = 0; fm < 4; ++fm)
                aF[fm] = *(const half8v*)(As + (wm + fm * 16 + cl) * 64 + vv);
#pragma unroll
            for (int fn = 0; fn < 4; ++fn)
                bF[fn] = *(const half8v*)(Bs + (wn + fn * 16 + cl) * 64 + vv);
#pragma unroll
            for (int fm = 0; fm < 4; ++fm)
#pragma unroll
                for (int fn = 0; fn < 4; ++fn)
                    acc[fm][fn] = __builtin_amdgcn_mfma_f32_16x16x32_f16(aF[fm], bF[fn], acc[fm][fn], 0, 0, 0);
        }
        __syncthreads();
    }

    _Float16* Tile = (_Float16*)smem;  // [128 slots][136]
#pragma unroll
    for (int fm = 0; fm < 4; ++fm) {
        int dl = wm + fm * 16 + g * 4;
#pragma unroll
        for (int fn = 0; fn < 4; ++fn) {
            int sl = wn + fn * 16 + cl;
            half4v hv;
#pragma unroll
            for (int j2 = 0; j2 < 4; ++j2) hv[j2] = (_Float16)acc[fm][fn][j2];
            *(half4v*)(&Tile[sl * 136 + dl]) = hv;
        }
    }
    __syncthreads();
#pragma unroll
    for (int p = 0; p < 8; ++p) {
        int r = p * 16 + (tid >> 4);
        int c8 = (tid & 15) * 8;
        if (row0 + r < n_e)
            *(half8v*)(Yh + ((size_t)kh * YSLOTS + T * 128 + r) * D + bx * 128 + c8) =
                *(const half8v*)(&Tile[r * 136 + c8]);
    }
}

__global__ void k_comb(const int* __restrict__ tk_e, const float* __restrict__ tk_w,
                       const int* __restrict__ tk_pos, const int* __restrict__ counts,
                       const _Float16* __restrict__ Yh, const float* __restrict__ b2,
                       float* __restrict__ out) {
    int idx = blockIdx.x * 256 + threadIdx.x;
    int t = idx >> 8;
    int d = (idx & 255) * 4;
    int offE[NE + 1];
    mk_offs(counts, offE);
    int e0 = tk_e[2 * t], e1 = tk_e[2 * t + 1];
    float w0 = tk_w[2 * t], w1 = tk_w[2 * t + 1];
    size_t s0 = offE[e0] + tk_pos[2 * t];
    size_t s1 = offE[e1] + tk_pos[2 * t + 1];
    half4v y00 = *(const half4v*)(Yh + s0 * D + d);
    half4v y01 = *(const half4v*)(Yh + ((size_t)YSLOTS + s0) * D + d);
    half4v y10 = *(const half4v*)(Yh + s1 * D + d);
    half4v y11 = *(const half4v*)(Yh + ((size_t)YSLOTS + s1) * D + d);
    float4 b20 = *(const float4*)(b2 + e0 * D + d);
    float4 b21 = *(const float4*)(b2 + e1 * D + d);
    float4 r;
    r.x = w0 * ((float)y00[0] + (float)y01[0] + b20.x) + w1 * ((float)y10[0] + (float)y11[0] + b21.x);
    r.y = w0 * ((float)y00[1] + (float)y01[1] + b20.y) + w1 * ((float)y10[1] + (float)y11[1] + b21.y);
    r.z = w0 * ((float)y00[2] + (float)y01[2] + b20.z) + w1 * ((float)y10[2] + (float)y11[2] + b21.z);
    r.w = w0 * ((float)y00[3] + (float)y01[3] + b20.w) + w1 * ((float)y10[3] + (float)y11[3] + b21.w);
    *(float4*)(out + (size_t)t * D + d) = r;
}

extern "C" void kernel_launch(void* const* d_in, const int* in_sizes, int n_in,
                              void* d_out, int out_size, void* d_ws, size_t ws_size,
                              hipStream_t stream) {
    const float* x  = (const float*)d_in[0];
    const float* W1 = (const float*)d_in[1];
    const float* b1 = (const float*)d_in[2];
    const float* W2 = (const float*)d_in[3];
    const float* b2 = (const float*)d_in[4];
    const float* Wg = (const float*)d_in[5];
    const float* bg = (const float*)d_in[6];
    float* out = (float*)d_out;

    char* ws = (char*)d_ws;
    int*   counts   = (int*)(ws);
    int*   tk_e     = (int*)(ws + 256);
    float* tk_w     = (float*)(ws + 33024);
    int*   tk_pos   = (int*)(ws + 65792);
    int*   tok_list = (int*)(ws + 98560);
    _Float16* xh    = (_Float16*)(ws + (1ull << 20));
    _Float16* W1t   = (_Float16*)(ws + (10ull << 20));
    _Float16* Yh    = (_Float16*)(ws + (10ull << 20));   // overlays W1t after ffn1
    _Float16* W2t   = (_Float16*)(ws + (74ull << 20));
    _Float16* H     = (_Float16*)(ws + (138ull << 20));

    hipMemsetAsync(counts, 0, 64, stream);
    k_gate_trw1<<<256 + 4096, 256, 0, stream>>>(x, Wg, bg, counts, tk_e, tk_w, tk_pos,
                                                tok_list, xh, W1, W1t);
    k_ffn1_trw2<<<2304 + 4096, 256, 0, stream>>>(xh, W1t, b1, counts, tok_list,
                                                 H, W2, W2t);
    k_ffn2<<<8 * 144, 256, 0, stream>>>(H, W2t, counts, Yh);
    k_comb<<<(TOK * D / 4) / 256, 256, 0, stream>>>(tk_e, tk_w, tk_pos, counts, Yh, b2, out);
}